// Round 6
// baseline (1123.289 us; speedup 1.0000x reference)
//
#include <hip/hip_runtime.h>
#include <stdint.h>

// GeneDynamics: out = -x + (A @ x^2) / (x^2 + 1)
// v6: ZERO-LDS register-direct structure. thread <-> row, so xh loads are
//     wave-uniform broadcasts (L2-hot); A streamed straight to VGPRs.
//     No barriers, no inline asm, no shuffles; latency hidden by 32 waves/CU.

#define NN 16384
#define DIM 16
#define TPB 256
#define BROWS 256              // rows per block (1 per thread)
#define NRB 64                 // NN / BROWS
#define KSPLIT 32
#define KRANGE 512             // NN / KSPLIT
#define NCH4 (KRANGE / 4)      // 128 chunks of 4 k

// prep: out = -x ; xh = x^2 ; inv = 1/(x^2+1)
__global__ __launch_bounds__(256) void prep_kernel(const float* __restrict__ x,
                                                   float* __restrict__ out,
                                                   float* __restrict__ xh,
                                                   float* __restrict__ inv) {
    int i = blockIdx.x * 256 + threadIdx.x;            // 65536 float4s
    float4 v = reinterpret_cast<const float4*>(x)[i];
    reinterpret_cast<float4*>(out)[i] = make_float4(-v.x, -v.y, -v.z, -v.w);
    float4 h = make_float4(v.x * v.x, v.y * v.y, v.z * v.z, v.w * v.w);
    reinterpret_cast<float4*>(xh)[i] = h;
    reinterpret_cast<float4*>(inv)[i] =
        make_float4(1.0f / (h.x + 1.0f), 1.0f / (h.y + 1.0f),
                    1.0f / (h.z + 1.0f), 1.0f / (h.w + 1.0f));
}

__global__ __launch_bounds__(TPB, 8) void agg_kernel(const float* __restrict__ A,
                                                     const float* __restrict__ xh,
                                                     const float* __restrict__ inv,
                                                     float* __restrict__ out) {
    const int tid = threadIdx.x;
    const int rb  = blockIdx.x & (NRB - 1);   // row-block (low bits: neighbors share xh window)
    const int ks  = blockIdx.x >> 6;          // k-split
    const int r   = rb * BROWS + tid;         // this thread's row
    const size_t k0 = (size_t)ks * KRANGE;

    const float4* __restrict__ Arow =
        reinterpret_cast<const float4*>(A + (size_t)r * NN + k0);
    const float4* __restrict__ X =
        reinterpret_cast<const float4*>(xh + k0 * DIM);   // wave-uniform stream

    float4 acc0 = make_float4(0.f, 0.f, 0.f, 0.f);
    float4 acc1 = make_float4(0.f, 0.f, 0.f, 0.f);
    float4 acc2 = make_float4(0.f, 0.f, 0.f, 0.f);
    float4 acc3 = make_float4(0.f, 0.f, 0.f, 0.f);

    for (int c = 0; c < NCH4; ++c) {
        const float4 a = Arow[c];                  // 16 B of this row (sequential)
        const float4* __restrict__ q = X + (size_t)c * 16;  // 4 k x 16 dims, uniform
        #pragma unroll
        for (int j = 0; j < 4; ++j) {
            const float aj = reinterpret_cast<const float*>(&a)[j];  // j is unroll-const
            float4 q0 = q[j * 4 + 0];
            float4 q1 = q[j * 4 + 1];
            float4 q2 = q[j * 4 + 2];
            float4 q3 = q[j * 4 + 3];
            acc0.x += aj * q0.x; acc0.y += aj * q0.y;
            acc0.z += aj * q0.z; acc0.w += aj * q0.w;
            acc1.x += aj * q1.x; acc1.y += aj * q1.y;
            acc1.z += aj * q1.z; acc1.w += aj * q1.w;
            acc2.x += aj * q2.x; acc2.y += aj * q2.y;
            acc2.z += aj * q2.z; acc2.w += aj * q2.w;
            acc3.x += aj * q3.x; acc3.y += aj * q3.y;
            acc3.z += aj * q3.z; acc3.w += aj * q3.w;
        }
    }

    // out += partial * inv   (epilogue linear in agg -> split-K via atomics is exact)
    const float4* iv4 = reinterpret_cast<const float4*>(inv + (size_t)r * DIM);
    float* orow = out + (size_t)r * DIM;
    {
        float4 iv = iv4[0];
        atomicAdd(&orow[0],  acc0.x * iv.x); atomicAdd(&orow[1],  acc0.y * iv.y);
        atomicAdd(&orow[2],  acc0.z * iv.z); atomicAdd(&orow[3],  acc0.w * iv.w);
    }
    {
        float4 iv = iv4[1];
        atomicAdd(&orow[4],  acc1.x * iv.x); atomicAdd(&orow[5],  acc1.y * iv.y);
        atomicAdd(&orow[6],  acc1.z * iv.z); atomicAdd(&orow[7],  acc1.w * iv.w);
    }
    {
        float4 iv = iv4[2];
        atomicAdd(&orow[8],  acc2.x * iv.x); atomicAdd(&orow[9],  acc2.y * iv.y);
        atomicAdd(&orow[10], acc2.z * iv.z); atomicAdd(&orow[11], acc2.w * iv.w);
    }
    {
        float4 iv = iv4[3];
        atomicAdd(&orow[12], acc3.x * iv.x); atomicAdd(&orow[13], acc3.y * iv.y);
        atomicAdd(&orow[14], acc3.z * iv.z); atomicAdd(&orow[15], acc3.w * iv.w);
    }
}

extern "C" void kernel_launch(void* const* d_in, const int* in_sizes, int n_in,
                              void* d_out, int out_size, void* d_ws, size_t ws_size,
                              hipStream_t stream) {
    const float* A = (const float*)d_in[0];
    const float* x = (const float*)d_in[1];
    float* out = (float*)d_out;
    float* xhp = (float*)d_ws;                      // 1 MiB
    float* inv = (float*)d_ws + (size_t)NN * DIM;   // 1 MiB

    prep_kernel<<<(NN * DIM / 4) / 256, 256, 0, stream>>>(x, out, xhp, inv);
    agg_kernel<<<NRB * KSPLIT, TPB, 0, stream>>>(A, xhp, inv, out);
}

// Round 7
// 535.688 us; speedup vs baseline: 2.0969x; 2.0969x over previous
//
#include <hip/hip_runtime.h>
#include <stdint.h>

// GeneDynamics: out = -x + (A @ x^2) / (x^2 + 1)
// v7: block-shared 64x128 tile; each global_load_lds16 = 2 rows x 512B
//     SEQUENTIAL bursts (DRAM-friendly); raw s_barrier + counted vmcnt(10)
//     keeps prefetch in flight; compute phase issues zero VMEM.

#define NN 16384
#define DIM 16
#define TPB 256                // 4 waves
#define ROWS 64                // rows per block
#define NRB 256                // NN / ROWS
#define KSPLIT 4
#define KRANGE 4096            // NN / KSPLIT
#define KC 128                 // k per chunk (512 B per row per chunk)
#define NCH 32                 // KRANGE / KC

// prep: out = -x ; xh = x^2 ; inv = 1/(x^2+1)
__global__ __launch_bounds__(256) void prep_kernel(const float* __restrict__ x,
                                                   float* __restrict__ out,
                                                   float* __restrict__ xh,
                                                   float* __restrict__ inv) {
    int i = blockIdx.x * 256 + threadIdx.x;            // 65536 float4s
    float4 v = reinterpret_cast<const float4*>(x)[i];
    reinterpret_cast<float4*>(out)[i] = make_float4(-v.x, -v.y, -v.z, -v.w);
    float4 h = make_float4(v.x * v.x, v.y * v.y, v.z * v.z, v.w * v.w);
    reinterpret_cast<float4*>(xh)[i] = h;
    reinterpret_cast<float4*>(inv)[i] =
        make_float4(1.0f / (h.x + 1.0f), 1.0f / (h.y + 1.0f),
                    1.0f / (h.z + 1.0f), 1.0f / (h.w + 1.0f));
}

__device__ __forceinline__ void gload_lds16(const float* g, float* l) {
    __builtin_amdgcn_global_load_lds(
        (const __attribute__((address_space(1))) void*)g,
        (__attribute__((address_space(3))) void*)l, 16, 0, 0);
}

__global__ __launch_bounds__(TPB) void agg_kernel(const float* __restrict__ A,
                                                  const float* __restrict__ xh,
                                                  const float* __restrict__ inv,
                                                  float* __restrict__ out) {
    // A tile [64 rows][128 k] row-major; row r's 32 float4-slots XOR-swizzled:
    //   physical slot p holds logical slot p ^ (r&7)   (involution, via source perm)
    // xh tile [128 k][4 d-slots]; physical d-slot dp of row k holds logical
    //   dp ^ ((k>>3)&3)  -> compute reads are 4 distinct bank-spans (conflict-free)
    __shared__ float ldsA[2][ROWS * KC];   // 2 x 32 KiB
    __shared__ float ldsX[2][KC * DIM];    // 2 x 8 KiB   (total 80 KiB -> 2 blk/CU)

    const int tid = threadIdx.x;
    const int l   = tid & 63;
    const int w   = tid >> 6;
    const int rb  = blockIdx.x & (NRB - 1);
    const int ks  = blockIdx.x >> 8;
    const int r0  = rb * ROWS;
    const size_t k0 = (size_t)ks * KRANGE;

    const int m  = tid & 15;        // row low bits (rows j*16+m)
    const int a  = tid >> 4;        // 0..15: this thread's 8-k phase
    const int c3 = a & 3;           // xh d-slot swizzle constant
    const int s7 = m & 7;           // A slot swizzle (row&7 == m&7 for rows j*16+m)

    // ---- A staging geometry: instr n = w*8+i covers tile rows 2n, 2n+1 ----
    // lane: hi = l>>5 -> row 2n+hi; phys slot l&31; src slot = (l&31) ^ ((2n+hi)&7)
    const int hi = l >> 5;
    const int p31 = l & 31;
    const float* Abase = A + (size_t)(r0 + (w << 4) + hi) * NN + k0;  // + 2i rows
    int aso[8];
    #pragma unroll
    for (int i = 0; i < 8; ++i)
        aso[i] = 4 * (p31 ^ ((2 * i + hi) & 7));     // (2n+hi)&7 == (2i+hi)&7

    // ---- xh staging geometry: instr i2 = w*2+i covers phys f4-slots i2*64+l ----
    int xso[2];
    #pragma unroll
    for (int i = 0; i < 2; ++i) {
        int p = (w * 2 + i) * 64 + l;
        xso[i] = (p >> 2) * 16 + 4 * ((p & 3) ^ ((p >> 5) & 3));
    }

    float4 acc[4][4];               // [row j][d-slot v]
    #pragma unroll
    for (int j = 0; j < 4; ++j)
        #pragma unroll
        for (int v = 0; v < 4; ++v) acc[j][v] = make_float4(0.f, 0.f, 0.f, 0.f);

#define STAGE(T, B)                                                           \
    {                                                                         \
        const float* sA = Abase + (size_t)(T) * KC;                           \
        _Pragma("unroll")                                                     \
        for (int i = 0; i < 8; ++i)                                           \
            gload_lds16(sA + (size_t)(2 * i) * NN + aso[i],                   \
                        &ldsA[B][(w * 8 + i) * 256]);                         \
        const float* sX = xh + (k0 + (size_t)(T) * KC) * DIM;                 \
        _Pragma("unroll")                                                     \
        for (int i = 0; i < 2; ++i)                                           \
            gload_lds16(sX + xso[i], &ldsX[B][(w * 2 + i) * 256]);            \
    }

#define COMPUTE(B)                                                            \
    {                                                                         \
        float4 fr[4][2];                                                      \
        const int ps0 = 4 * ((2 * a) ^ s7);                                   \
        const int ps1 = 4 * ((2 * a + 1) ^ s7);                               \
        _Pragma("unroll")                                                     \
        for (int j = 0; j < 4; ++j) {                                         \
            const float* rbse = &ldsA[B][(j * 16 + m) * KC];                  \
            fr[j][0] = *reinterpret_cast<const float4*>(rbse + ps0);          \
            fr[j][1] = *reinterpret_cast<const float4*>(rbse + ps1);          \
        }                                                                     \
        const float* xb = &ldsX[B][a * 128];                                  \
        _Pragma("unroll")                                                     \
        for (int kk = 0; kk < 8; ++kk) {                                      \
            float4 q0 = *reinterpret_cast<const float4*>(xb + kk * 16 + 4 * (0 ^ c3)); \
            float4 q1 = *reinterpret_cast<const float4*>(xb + kk * 16 + 4 * (1 ^ c3)); \
            float4 q2 = *reinterpret_cast<const float4*>(xb + kk * 16 + 4 * (2 ^ c3)); \
            float4 q3 = *reinterpret_cast<const float4*>(xb + kk * 16 + 4 * (3 ^ c3)); \
            _Pragma("unroll")                                                 \
            for (int j = 0; j < 4; ++j) {                                     \
                float aj = reinterpret_cast<const float*>(&fr[j][kk >> 2])[kk & 3]; \
                acc[j][0].x += aj * q0.x; acc[j][0].y += aj * q0.y;           \
                acc[j][0].z += aj * q0.z; acc[j][0].w += aj * q0.w;           \
                acc[j][1].x += aj * q1.x; acc[j][1].y += aj * q1.y;           \
                acc[j][1].z += aj * q1.z; acc[j][1].w += aj * q1.w;           \
                acc[j][2].x += aj * q2.x; acc[j][2].y += aj * q2.y;           \
                acc[j][2].z += aj * q2.z; acc[j][2].w += aj * q2.w;           \
                acc[j][3].x += aj * q3.x; acc[j][3].y += aj * q3.y;           \
                acc[j][3].z += aj * q3.z; acc[j][3].w += aj * q3.w;           \
            }                                                                 \
        }                                                                     \
    }

    STAGE(0, 0);
    for (int t = 0; t < NCH; ++t) {
        const int b = t & 1;
        if (t + 1 < NCH) {
            asm volatile("s_waitcnt lgkmcnt(0)" ::: "memory");   // my reads of buf b^1 done
            __builtin_amdgcn_sched_barrier(0);
            __builtin_amdgcn_s_barrier();                        // everyone done reading b^1
            STAGE(t + 1, b ^ 1);
            asm volatile("s_waitcnt vmcnt(10)" ::: "memory");    // my chunk-t loads arrived
            __builtin_amdgcn_sched_barrier(0);
            __builtin_amdgcn_s_barrier();                        // all chunk-t data resident
        } else {
            asm volatile("s_waitcnt vmcnt(0)" ::: "memory");
            __builtin_amdgcn_sched_barrier(0);
            __builtin_amdgcn_s_barrier();
        }
        COMPUTE(b);
    }

    // ---- merge k-phases a (bits 4,5 of tid) via butterfly ----
    #pragma unroll
    for (int j = 0; j < 4; ++j)
        #pragma unroll
        for (int v = 0; v < 4; ++v) {
            acc[j][v].x += __shfl_xor(acc[j][v].x, 16);
            acc[j][v].y += __shfl_xor(acc[j][v].y, 16);
            acc[j][v].z += __shfl_xor(acc[j][v].z, 16);
            acc[j][v].w += __shfl_xor(acc[j][v].w, 16);
        }
    #pragma unroll
    for (int j = 0; j < 4; ++j)
        #pragma unroll
        for (int v = 0; v < 4; ++v) {
            acc[j][v].x += __shfl_xor(acc[j][v].x, 32);
            acc[j][v].y += __shfl_xor(acc[j][v].y, 32);
            acc[j][v].z += __shfl_xor(acc[j][v].z, 32);
            acc[j][v].w += __shfl_xor(acc[j][v].w, 32);
        }

    // one representative 16-lane group per wave writes; KSPLIT x 4 waves
    // partials sum via atomics (epilogue linear in agg -> exact)
    if ((l >> 4) == 0) {
        #pragma unroll
        for (int j = 0; j < 4; ++j) {
            const int R = r0 + j * 16 + m;
            const float4* iv4 = reinterpret_cast<const float4*>(inv + (size_t)R * DIM);
            float* orow = out + (size_t)R * DIM;
            #pragma unroll
            for (int v = 0; v < 4; ++v) {
                float4 iv = iv4[v];
                atomicAdd(&orow[4 * v + 0], acc[j][v].x * iv.x);
                atomicAdd(&orow[4 * v + 1], acc[j][v].y * iv.y);
                atomicAdd(&orow[4 * v + 2], acc[j][v].z * iv.z);
                atomicAdd(&orow[4 * v + 3], acc[j][v].w * iv.w);
            }
        }
    }
#undef STAGE
#undef COMPUTE
}

extern "C" void kernel_launch(void* const* d_in, const int* in_sizes, int n_in,
                              void* d_out, int out_size, void* d_ws, size_t ws_size,
                              hipStream_t stream) {
    const float* A = (const float*)d_in[0];
    const float* x = (const float*)d_in[1];
    float* out = (float*)d_out;
    float* xhp = (float*)d_ws;                      // 1 MiB
    float* inv = (float*)d_ws + (size_t)NN * DIM;   // 1 MiB

    prep_kernel<<<(NN * DIM / 4) / 256, 256, 0, stream>>>(x, out, xhp, inv);
    agg_kernel<<<NRB * KSPLIT, TPB, 0, stream>>>(A, xhp, inv, out);
}